// Round 7
// baseline (766.246 us; speedup 1.0000x reference)
//
#include <hip/hip_runtime.h>
#include <math.h>

#define N_NODES 20000
#define N_PAD 20096            // N_NODES rounded up to 128 (GEMM M-tile)
#define N_EDGES 320000
#define IN_CH 512
#define HEADS 4
#define OUT_CH 128
#define HC 512                 // HEADS*OUT_CH
#define NEG_SLOPE 0.2f

// fusedA block partitions
#define CVX_BLOCKS 5024        // N_PAD*IN_CH/8/256
#define CVW_BLOCKS 64          // (IN_CH/64)*(HC/64)
#define CNT_BLOCKS 1250        // N_EDGES/256
#define FA_BLOCKS  (CVX_BLOCKS + CVW_BLOCKS + CNT_BLOCKS)

typedef __attribute__((ext_vector_type(8))) short short8;
typedef __attribute__((ext_vector_type(4))) float float4v;

// ---------------- edge-index dtype detection (inline, deterministic) ----------------
__device__ __forceinline__ int detect_is64(const int* __restrict__ ei32) {
    int is64 = 1;
    #pragma unroll
    for (int i = 0; i < 32; i++) is64 &= (ei32[2 * i + 1] == 0);
    return is64;
}

__device__ __forceinline__ int edge_at(const void* ei, int is64, long long idx) {
    return is64 ? (int)((const long long*)ei)[idx] : ((const int*)ei)[idx];
}

__device__ __forceinline__ unsigned short f2bf(float f) {
    union { float f; unsigned u; } v; v.f = f;
    unsigned r = v.u + 0x7fffu + ((v.u >> 16) & 1u);   // RNE
    return (unsigned short)(r >> 16);
}

// decode 8 packed bf16 (uint4) -> 8 floats
__device__ __forceinline__ void bf8_decode(uint4 r, float* f) {
    f[0] = __uint_as_float(r.x << 16); f[1] = __uint_as_float(r.x & 0xffff0000u);
    f[2] = __uint_as_float(r.y << 16); f[3] = __uint_as_float(r.y & 0xffff0000u);
    f[4] = __uint_as_float(r.z << 16); f[5] = __uint_as_float(r.z & 0xffff0000u);
    f[6] = __uint_as_float(r.w << 16); f[7] = __uint_as_float(r.w & 0xffff0000u);
}

__device__ __forceinline__ float leaky(float t) { return t > 0.f ? t : NEG_SLOPE * t; }

__device__ __forceinline__ float sel_head(float4 w, int hd) {
    float lo = (hd & 1) ? w.y : w.x;
    float hi = (hd & 1) ? w.w : w.z;
    return (hd & 2) ? hi : lo;
}

// ---------------- K1: convert_x + convert_w(transpose) + count, last block scans ----
__global__ __launch_bounds__(256) void fusedA_kernel(const float* __restrict__ x,
                                                     const float* __restrict__ W,
                                                     unsigned short* __restrict__ xb,
                                                     unsigned short* __restrict__ Wt,
                                                     const void* __restrict__ ei,
                                                     int* __restrict__ counts,
                                                     int* __restrict__ done,
                                                     int* __restrict__ offsets) {
    __shared__ float tile[64][65];
    int b = blockIdx.x;
    int t = threadIdx.x;
    if (b < CVX_BLOCKS) {
        // ---- convert x -> bf16 (padded rows zeroed) ----
        size_t i = ((size_t)b * 256 + t) * 8;
        unsigned short o[8];
        if (i < (size_t)N_NODES * IN_CH) {
            float4 f0 = *(const float4*)&x[i];
            float4 f1 = *(const float4*)&x[i + 4];
            o[0] = f2bf(f0.x); o[1] = f2bf(f0.y); o[2] = f2bf(f0.z); o[3] = f2bf(f0.w);
            o[4] = f2bf(f1.x); o[5] = f2bf(f1.y); o[6] = f2bf(f1.z); o[7] = f2bf(f1.w);
        } else {
            for (int k = 0; k < 8; k++) o[k] = 0;
        }
        *(short8*)&xb[i] = *(short8*)o;
    } else if (b < CVX_BLOCKS + CVW_BLOCKS) {
        // ---- W[K][N] -> Wt[N][K] bf16 via LDS transpose ----
        int idx = b - CVX_BLOCKS;
        int k0 = (idx & 7) * 64, n0 = (idx >> 3) * 64;
        int r = t >> 6, c = t & 63;
        for (int rr = r; rr < 64; rr += 4)
            tile[rr][c] = W[(size_t)(k0 + rr) * HC + n0 + c];
        __syncthreads();
        for (int rr = r; rr < 64; rr += 4)
            Wt[(size_t)(n0 + rr) * IN_CH + k0 + c] = f2bf(tile[c][rr]);
    } else {
        // ---- count incoming edges per dst ----
        int is64 = detect_is64((const int*)ei);
        int e = (b - CVX_BLOCKS - CVW_BLOCKS) * 256 + t;
        if (e < N_EDGES) {
            int dst = edge_at(ei, is64, (long long)N_EDGES + e);
            atomicAdd(&counts[dst], 1);
        }
    }

    // ---- last finishing block performs the exclusive scan ----
    __syncthreads();
    __threadfence();                       // release: publish counts/xb/Wt
    __shared__ int lastFlag;
    if (t == 0) lastFlag = (atomicAdd(done, 1) == FA_BLOCKS - 1);
    __syncthreads();
    if (!lastFlag) return;
    __threadfence();                       // acquire: see all counts

    const int CHUNK = 80;                  // 256*80 = 20480 >= N_NODES
    int base = t * CHUNK;
    int sum = 0;
    for (int k = 0; k < CHUNK; k++) {
        int i = base + k;
        sum += (i < N_NODES) ? counts[i] : 0;
    }
    int lane = t & 63, wv = t >> 6;
    int s = sum;
    #pragma unroll
    for (int off = 1; off < 64; off <<= 1) {
        int u = __shfl_up(s, off, 64);
        if (lane >= off) s += u;
    }
    __shared__ int wsum[4], wexcl[4];
    if (lane == 63) wsum[wv] = s;
    __syncthreads();
    if (t < 4) {
        int acc = 0;
        for (int j = 0; j < t; j++) acc += wsum[j];
        wexcl[t] = acc;
    }
    __syncthreads();
    int run = wexcl[wv] + s - sum;         // exclusive prefix of this thread's chunk
    for (int k = 0; k < CHUNK; k++) {
        int i = base + k;
        if (i < N_NODES) { offsets[i] = run; run += counts[i]; }
    }
    if (t == 255) offsets[N_NODES] = wexcl[3] + s;
}

// ---------------- K2: bf16 MFMA GEMM + fused attention halves ----------------
// 128x128 tile, BK=32, 256 threads. Block col bn covers exactly head bn -> the
// epilogue computes complete a_s/a_d[row][head bn] from fp32 accumulators.
__global__ __launch_bounds__(256) void gemm_kernel(const unsigned short* __restrict__ A,
                                                   const unsigned short* __restrict__ Bt,
                                                   unsigned short* __restrict__ Cb,
                                                   const float* __restrict__ att_s_g,
                                                   const float* __restrict__ att_d_g,
                                                   float* __restrict__ a_s,
                                                   float* __restrict__ a_d) {
    __shared__ __align__(16) unsigned short As[128 * 32];
    __shared__ __align__(16) unsigned short Bs[128 * 32];
    __shared__ float red_s[4][64], red_d[4][64];
    const int head = blockIdx.x;
    const int bn = head * 128;
    const int bm = blockIdx.y * 128;
    const int t = threadIdx.x;
    const int wv = t >> 6, lane = t & 63;
    const int wm = wv & 1, wn = wv >> 1;
    const int lm = lane & 15, lk = lane >> 4;

    float4v acc[4][4];
    #pragma unroll
    for (int i = 0; i < 4; i++)
        #pragma unroll
        for (int j = 0; j < 4; j++) acc[i][j] = (float4v){0.f, 0.f, 0.f, 0.f};

    const int srow = t >> 2;
    const int skof = (t & 3) * 8;

    for (int k0 = 0; k0 < IN_CH; k0 += 32) {
        __syncthreads();
        #pragma unroll
        for (int q = 0; q < 2; q++) {
            const unsigned short* gA = A + (size_t)(bm + q * 64 + srow) * IN_CH + k0 + skof;
            const unsigned short* gB = Bt + (size_t)(bn + q * 64 + srow) * IN_CH + k0 + skof;
            __builtin_amdgcn_global_load_lds((const __attribute__((address_space(1))) void*)gA,
                                             (__attribute__((address_space(3))) void*)&As[q * 2048 + t * 8], 16, 0, 0);
            __builtin_amdgcn_global_load_lds((const __attribute__((address_space(1))) void*)gB,
                                             (__attribute__((address_space(3))) void*)&Bs[q * 2048 + t * 8], 16, 0, 0);
        }
        __syncthreads();

        short8 af[4], bf[4];
        #pragma unroll
        for (int i = 0; i < 4; i++)
            af[i] = *(const short8*)&As[(wm * 64 + i * 16 + lm) * 32 + lk * 8];
        #pragma unroll
        for (int j = 0; j < 4; j++)
            bf[j] = *(const short8*)&Bs[(wn * 64 + j * 16 + lm) * 32 + lk * 8];
        #pragma unroll
        for (int i = 0; i < 4; i++)
            #pragma unroll
            for (int j = 0; j < 4; j++)
                acc[i][j] = __builtin_amdgcn_mfma_f32_16x16x32_bf16(af[i], bf[j], acc[i][j], 0, 0, 0);
    }

    // ---- C write (C/D layout: col = lane&15, row = (lane>>4)*4 + reg) ----
    #pragma unroll
    for (int i = 0; i < 4; i++) {
        #pragma unroll
        for (int r = 0; r < 4; r++) {
            int row = bm + wm * 64 + i * 16 + lk * 4 + r;
            if (row < N_NODES) {
                #pragma unroll
                for (int j = 0; j < 4; j++) {
                    int col = bn + wn * 64 + j * 16 + lm;
                    Cb[(size_t)row * HC + col] = f2bf(acc[i][j][r]);
                }
            }
        }
    }

    // ---- fused attention halves from fp32 accumulators ----
    float asv[4], adv[4];
    #pragma unroll
    for (int j = 0; j < 4; j++) {
        int col = bn + wn * 64 + j * 16 + lm;
        asv[j] = att_s_g[col];
        adv[j] = att_d_g[col];
    }
    #pragma unroll
    for (int i = 0; i < 4; i++) {
        #pragma unroll
        for (int r = 0; r < 4; r++) {
            float s = acc[i][0][r] * asv[0] + acc[i][1][r] * asv[1]
                    + acc[i][2][r] * asv[2] + acc[i][3][r] * asv[3];
            float d = acc[i][0][r] * adv[0] + acc[i][1][r] * adv[1]
                    + acc[i][2][r] * adv[2] + acc[i][3][r] * adv[3];
            #pragma unroll
            for (int off = 1; off < 16; off <<= 1) {   // reduce over lm
                s += __shfl_xor(s, off, 64);
                d += __shfl_xor(d, off, 64);
            }
            if (lm == 0) {
                red_s[wv][i * 16 + lk * 4 + r] = s;
                red_d[wv][i * 16 + lk * 4 + r] = d;
            }
        }
    }
    __syncthreads();
    if (t < 128) {
        int wm2 = t >> 6, row = t & 63;      // waves wm2 and wm2+2 share rows
        int grow = bm + wm2 * 64 + row;
        if (grow < N_NODES) {
            a_s[grow * 4 + head] = red_s[wm2][row] + red_s[wm2 + 2][row];
            a_d[grow * 4 + head] = red_d[wm2][row] + red_d[wm2 + 2][row];
        }
    }
}

// ---------------- K3: pure scatter ----------------
__global__ __launch_bounds__(256) void scatter_kernel(const void* __restrict__ ei,
                                                      const int* __restrict__ offsets,
                                                      int* __restrict__ cursor,
                                                      int* __restrict__ sorted_src) {
    int is64 = detect_is64((const int*)ei);
    int e = blockIdx.x * 256 + threadIdx.x;
    if (e < N_EDGES) {
        int dst = edge_at(ei, is64, (long long)N_EDGES + e);
        int src = edge_at(ei, is64, e);
        int pos = offsets[dst] + atomicAdd(&cursor[dst], 1);
        if ((unsigned)pos < N_EDGES) sorted_src[pos] = src;   // guard vs replay artifacts
    }
}

// ---------------- K4: segment softmax + weighted gather ----------------
// 2 waves per node (alternating 4-edge chunks), partials combined via LDS.
// Weights computed inline: w = exp(leaky(a_s[src]+a_d[node])). No max subtraction
// (logits bounded ~|8|; fp32 exp safe; algebraically identical).
__global__ __launch_bounds__(256) void gather_kernel(const unsigned short* __restrict__ xlb,
                                                     const float* __restrict__ a_s,
                                                     const float* __restrict__ a_d,
                                                     const int* __restrict__ offsets,
                                                     const int* __restrict__ sorted_src,
                                                     const float* __restrict__ bias,
                                                     float* __restrict__ out) {
    __shared__ float cl[2][64][9];
    int wv = threadIdx.x >> 6;
    int nib = wv >> 1;
    int sub = wv & 1;
    int node = blockIdx.x * 2 + nib;    // grid = N_NODES/2
    int lane = threadIdx.x & 63;
    int hd = lane >> 4;
    int beg = offsets[node], end = offsets[node + 1];

    const unsigned short* xrow = xlb + lane * 8;
    float adh = a_d[node * 4 + hd];
    float acc[8] = {0, 0, 0, 0, 0, 0, 0, 0};
    float denom = 0.f;

    if (sub == 0) {   // self-loop
        float w = __expf(leaky(a_s[node * 4 + hd] + adh));
        denom = w;
        uint4 r = *(const uint4*)(xrow + (size_t)node * HC);
        float f[8];
        bf8_decode(r, f);
        #pragma unroll
        for (int k = 0; k < 8; k++) acc[k] = w * f[k];
    }

    for (int c0 = beg + sub * 4; c0 < end; c0 += 8) {
        int n = end - c0;
        if (n >= 4) {
            int s0 = sorted_src[c0];
            int s1 = sorted_src[c0 + 1];
            int s2 = sorted_src[c0 + 2];
            int s3 = sorted_src[c0 + 3];
            s0 = ((unsigned)s0 < N_NODES) ? s0 : 0;   // guard vs replay artifacts
            s1 = ((unsigned)s1 < N_NODES) ? s1 : 0;
            s2 = ((unsigned)s2 < N_NODES) ? s2 : 0;
            s3 = ((unsigned)s3 < N_NODES) ? s3 : 0;
            uint4 r0 = *(const uint4*)(xrow + (size_t)s0 * HC);
            uint4 r1 = *(const uint4*)(xrow + (size_t)s1 * HC);
            uint4 r2 = *(const uint4*)(xrow + (size_t)s2 * HC);
            uint4 r3 = *(const uint4*)(xrow + (size_t)s3 * HC);
            float w0 = __expf(leaky(a_s[s0 * 4 + hd] + adh));
            float w1 = __expf(leaky(a_s[s1 * 4 + hd] + adh));
            float w2 = __expf(leaky(a_s[s2 * 4 + hd] + adh));
            float w3 = __expf(leaky(a_s[s3 * 4 + hd] + adh));
            denom += (w0 + w1) + (w2 + w3);
            float f0[8], f1[8], f2[8], f3[8];
            bf8_decode(r0, f0);
            bf8_decode(r1, f1);
            bf8_decode(r2, f2);
            bf8_decode(r3, f3);
            #pragma unroll
            for (int k = 0; k < 8; k++)
                acc[k] += (w0 * f0[k] + w1 * f1[k]) + (w2 * f2[k] + w3 * f3[k]);
        } else {
            for (int j = 0; j < n; j++) {
                int s0 = sorted_src[c0 + j];
                s0 = ((unsigned)s0 < N_NODES) ? s0 : 0;
                uint4 r0 = *(const uint4*)(xrow + (size_t)s0 * HC);
                float w0 = __expf(leaky(a_s[s0 * 4 + hd] + adh));
                denom += w0;
                float f0[8];
                bf8_decode(r0, f0);
                #pragma unroll
                for (int k = 0; k < 8; k++) acc[k] += w0 * f0[k];
            }
        }
    }

    if (sub == 1) {
        #pragma unroll
        for (int k = 0; k < 8; k++) cl[nib][lane][k] = acc[k];
        cl[nib][lane][8] = denom;
    }
    __syncthreads();
    if (sub == 0) {
        #pragma unroll
        for (int k = 0; k < 8; k++) acc[k] += cl[nib][lane][k];
        denom += cl[nib][lane][8];

        float rd = 0.25f / (denom + 1e-16f);   // fold head-mean into normalize
        float v[8];
        #pragma unroll
        for (int k = 0; k < 8; k++) {
            float t = acc[k] * rd;
            t += __shfl_xor(t, 16, 64);
            t += __shfl_xor(t, 32, 64);
            v[k] = t;
        }
        if (hd == 0) {
            float4 b0 = *(const float4*)&bias[lane * 8];
            float4 b1 = *(const float4*)&bias[lane * 8 + 4];
            float o[8];
            o[0] = v[0] + b0.x; o[1] = v[1] + b0.y; o[2] = v[2] + b0.z; o[3] = v[3] + b0.w;
            o[4] = v[4] + b1.x; o[5] = v[5] + b1.y; o[6] = v[6] + b1.z; o[7] = v[7] + b1.w;
            #pragma unroll
            for (int k = 0; k < 8; k++) o[k] = o[k] > 0.f ? o[k] : expm1f(o[k]);
            *(float4*)&out[(size_t)node * OUT_CH + lane * 8]     = make_float4(o[0], o[1], o[2], o[3]);
            *(float4*)&out[(size_t)node * OUT_CH + lane * 8 + 4] = make_float4(o[4], o[5], o[6], o[7]);
        }
    }
}

// ---------------- launch ----------------
extern "C" void kernel_launch(void* const* d_in, const int* in_sizes, int n_in,
                              void* d_out, int out_size, void* d_ws, size_t ws_size,
                              hipStream_t stream) {
    const float* x       = (const float*)d_in[0];
    const float* W       = (const float*)d_in[1];
    const float* att_src = (const float*)d_in[2];
    const float* att_dst = (const float*)d_in[3];
    const float* bias    = (const float*)d_in[4];
    const void*  ei      = d_in[5];
    float* out = (float*)d_out;

    char* ws = (char*)d_ws;
    size_t off = 0;
    unsigned short* xlb = (unsigned short*)(ws + off); off += (size_t)N_PAD * HC * sizeof(unsigned short);
    float* a_s     = (float*)(ws + off); off += (size_t)N_NODES * HEADS * sizeof(float);
    float* a_d     = (float*)(ws + off); off += (size_t)N_NODES * HEADS * sizeof(float);
    int* counts    = (int*)(ws + off);   off += (size_t)N_NODES * sizeof(int);
    int* cursor    = (int*)(ws + off);   off += (size_t)N_NODES * sizeof(int);   // contiguous with counts
    int* done      = (int*)(ws + off);   off += sizeof(int);                     // contiguous with cursor
    int* offsets   = (int*)(ws + off);   off += (size_t)(N_NODES + 1) * sizeof(int);
    off = (off + 15) & ~(size_t)15;
    int* sorted_src = (int*)(ws + off);  off += (size_t)N_EDGES * sizeof(int);
    off = (off + 15) & ~(size_t)15;
    unsigned short* xb = (unsigned short*)(ws + off); off += (size_t)N_PAD * IN_CH * sizeof(unsigned short);
    unsigned short* Wt = (unsigned short*)(ws + off); off += (size_t)IN_CH * HC * sizeof(unsigned short);

    hipMemsetAsync(counts, 0, (2u * N_NODES + 1) * sizeof(int), stream);   // counts + cursor + done
    fusedA_kernel<<<FA_BLOCKS, 256, 0, stream>>>(x, W, xb, Wt, ei, counts, done, offsets);
    gemm_kernel<<<dim3(HC / 128, N_PAD / 128), 256, 0, stream>>>(xb, Wt, xlb, att_src, att_dst, a_s, a_d);
    scatter_kernel<<<(N_EDGES + 255) / 256, 256, 0, stream>>>(ei, offsets, cursor, sorted_src);
    gather_kernel<<<N_NODES / 2, 256, 0, stream>>>(xlb, a_s, a_d, offsets, sorted_src, bias, out);
}

// Round 8
// 225.463 us; speedup vs baseline: 3.3986x; 3.3986x over previous
//
#include <hip/hip_runtime.h>
#include <math.h>

#define N_NODES 20000
#define N_PAD 20096            // N_NODES rounded up to 128 (GEMM M-tile)
#define N_EDGES 320000
#define IN_CH 512
#define HEADS 4
#define OUT_CH 128
#define HC 512                 // HEADS*OUT_CH
#define NEG_SLOPE 0.2f

// fusedA block partitions
#define CVX_BLOCKS 5024        // N_PAD*IN_CH/8/256
#define CVW_BLOCKS 64          // (IN_CH/64)*(HC/64)
#define CNT_BLOCKS 1250        // N_EDGES/256
#define FA_BLOCKS  (CVX_BLOCKS + CVW_BLOCKS + CNT_BLOCKS)

typedef __attribute__((ext_vector_type(8))) short short8;
typedef __attribute__((ext_vector_type(4))) float float4v;

// ---------------- edge-index dtype detection (inline, deterministic) ----------------
__device__ __forceinline__ int detect_is64(const int* __restrict__ ei32) {
    int is64 = 1;
    #pragma unroll
    for (int i = 0; i < 32; i++) is64 &= (ei32[2 * i + 1] == 0);
    return is64;
}

__device__ __forceinline__ int edge_at(const void* ei, int is64, long long idx) {
    return is64 ? (int)((const long long*)ei)[idx] : ((const int*)ei)[idx];
}

__device__ __forceinline__ unsigned short f2bf(float f) {
    union { float f; unsigned u; } v; v.f = f;
    unsigned r = v.u + 0x7fffu + ((v.u >> 16) & 1u);   // RNE
    return (unsigned short)(r >> 16);
}

// decode 8 packed bf16 (uint4) -> 8 floats
__device__ __forceinline__ void bf8_decode(uint4 r, float* f) {
    f[0] = __uint_as_float(r.x << 16); f[1] = __uint_as_float(r.x & 0xffff0000u);
    f[2] = __uint_as_float(r.y << 16); f[3] = __uint_as_float(r.y & 0xffff0000u);
    f[4] = __uint_as_float(r.z << 16); f[5] = __uint_as_float(r.z & 0xffff0000u);
    f[6] = __uint_as_float(r.w << 16); f[7] = __uint_as_float(r.w & 0xffff0000u);
}

__device__ __forceinline__ float leaky(float t) { return t > 0.f ? t : NEG_SLOPE * t; }

// ---------------- K1: convert_x + convert_w(transpose) + count ----------------
// NOTE: no device-scope fences here — round 7 showed a __threadfence() on every
// block's exit path costs ~100ns×blocks of serialized L2 writeback on CDNA4.
__global__ __launch_bounds__(256) void fusedA_kernel(const float* __restrict__ x,
                                                     const float* __restrict__ W,
                                                     unsigned short* __restrict__ xb,
                                                     unsigned short* __restrict__ Wt,
                                                     const void* __restrict__ ei,
                                                     int* __restrict__ counts) {
    __shared__ float tile[64][65];
    int b = blockIdx.x;
    int t = threadIdx.x;
    if (b < CVX_BLOCKS) {
        // ---- convert x -> bf16 (padded rows zeroed) ----
        size_t i = ((size_t)b * 256 + t) * 8;
        unsigned short o[8];
        if (i < (size_t)N_NODES * IN_CH) {
            float4 f0 = *(const float4*)&x[i];
            float4 f1 = *(const float4*)&x[i + 4];
            o[0] = f2bf(f0.x); o[1] = f2bf(f0.y); o[2] = f2bf(f0.z); o[3] = f2bf(f0.w);
            o[4] = f2bf(f1.x); o[5] = f2bf(f1.y); o[6] = f2bf(f1.z); o[7] = f2bf(f1.w);
        } else {
            for (int k = 0; k < 8; k++) o[k] = 0;
        }
        *(short8*)&xb[i] = *(short8*)o;
    } else if (b < CVX_BLOCKS + CVW_BLOCKS) {
        // ---- W[K][N] -> Wt[N][K] bf16 via LDS transpose ----
        int idx = b - CVX_BLOCKS;
        int k0 = (idx & 7) * 64, n0 = (idx >> 3) * 64;
        int r = t >> 6, c = t & 63;
        for (int rr = r; rr < 64; rr += 4)
            tile[rr][c] = W[(size_t)(k0 + rr) * HC + n0 + c];
        __syncthreads();
        for (int rr = r; rr < 64; rr += 4)
            Wt[(size_t)(n0 + rr) * IN_CH + k0 + c] = f2bf(tile[c][rr]);
    } else {
        // ---- count incoming edges per dst ----
        int is64 = detect_is64((const int*)ei);
        int e = (b - CVX_BLOCKS - CVW_BLOCKS) * 256 + t;
        if (e < N_EDGES) {
            int dst = edge_at(ei, is64, (long long)N_EDGES + e);
            atomicAdd(&counts[dst], 1);
        }
    }
}

// ---------------- K2: bf16 MFMA GEMM + fused attention halves ----------------
// 128x128 tile, BK=32, 256 threads. Block col bn covers exactly head bn -> the
// epilogue computes complete a_s/a_d[row][head bn] from fp32 accumulators.
__global__ __launch_bounds__(256) void gemm_kernel(const unsigned short* __restrict__ A,
                                                   const unsigned short* __restrict__ Bt,
                                                   unsigned short* __restrict__ Cb,
                                                   const float* __restrict__ att_s_g,
                                                   const float* __restrict__ att_d_g,
                                                   float* __restrict__ a_s,
                                                   float* __restrict__ a_d) {
    __shared__ __align__(16) unsigned short As[128 * 32];
    __shared__ __align__(16) unsigned short Bs[128 * 32];
    __shared__ float red_s[4][64], red_d[4][64];
    const int head = blockIdx.x;
    const int bn = head * 128;
    const int bm = blockIdx.y * 128;
    const int t = threadIdx.x;
    const int wv = t >> 6, lane = t & 63;
    const int wm = wv & 1, wn = wv >> 1;
    const int lm = lane & 15, lk = lane >> 4;

    float4v acc[4][4];
    #pragma unroll
    for (int i = 0; i < 4; i++)
        #pragma unroll
        for (int j = 0; j < 4; j++) acc[i][j] = (float4v){0.f, 0.f, 0.f, 0.f};

    const int srow = t >> 2;
    const int skof = (t & 3) * 8;

    for (int k0 = 0; k0 < IN_CH; k0 += 32) {
        __syncthreads();
        #pragma unroll
        for (int q = 0; q < 2; q++) {
            const unsigned short* gA = A + (size_t)(bm + q * 64 + srow) * IN_CH + k0 + skof;
            const unsigned short* gB = Bt + (size_t)(bn + q * 64 + srow) * IN_CH + k0 + skof;
            __builtin_amdgcn_global_load_lds((const __attribute__((address_space(1))) void*)gA,
                                             (__attribute__((address_space(3))) void*)&As[q * 2048 + t * 8], 16, 0, 0);
            __builtin_amdgcn_global_load_lds((const __attribute__((address_space(1))) void*)gB,
                                             (__attribute__((address_space(3))) void*)&Bs[q * 2048 + t * 8], 16, 0, 0);
        }
        __syncthreads();

        short8 af[4], bf[4];
        #pragma unroll
        for (int i = 0; i < 4; i++)
            af[i] = *(const short8*)&As[(wm * 64 + i * 16 + lm) * 32 + lk * 8];
        #pragma unroll
        for (int j = 0; j < 4; j++)
            bf[j] = *(const short8*)&Bs[(wn * 64 + j * 16 + lm) * 32 + lk * 8];
        #pragma unroll
        for (int i = 0; i < 4; i++)
            #pragma unroll
            for (int j = 0; j < 4; j++)
                acc[i][j] = __builtin_amdgcn_mfma_f32_16x16x32_bf16(af[i], bf[j], acc[i][j], 0, 0, 0);
    }

    // ---- C write (C/D layout: col = lane&15, row = (lane>>4)*4 + reg) ----
    #pragma unroll
    for (int i = 0; i < 4; i++) {
        #pragma unroll
        for (int r = 0; r < 4; r++) {
            int row = bm + wm * 64 + i * 16 + lk * 4 + r;
            if (row < N_NODES) {
                #pragma unroll
                for (int j = 0; j < 4; j++) {
                    int col = bn + wn * 64 + j * 16 + lm;
                    Cb[(size_t)row * HC + col] = f2bf(acc[i][j][r]);
                }
            }
        }
    }

    // ---- fused attention halves from fp32 accumulators ----
    float asv[4], adv[4];
    #pragma unroll
    for (int j = 0; j < 4; j++) {
        int col = bn + wn * 64 + j * 16 + lm;
        asv[j] = att_s_g[col];
        adv[j] = att_d_g[col];
    }
    #pragma unroll
    for (int i = 0; i < 4; i++) {
        #pragma unroll
        for (int r = 0; r < 4; r++) {
            float s = acc[i][0][r] * asv[0] + acc[i][1][r] * asv[1]
                    + acc[i][2][r] * asv[2] + acc[i][3][r] * asv[3];
            float d = acc[i][0][r] * adv[0] + acc[i][1][r] * adv[1]
                    + acc[i][2][r] * adv[2] + acc[i][3][r] * adv[3];
            #pragma unroll
            for (int off = 1; off < 16; off <<= 1) {   // reduce over lm
                s += __shfl_xor(s, off, 64);
                d += __shfl_xor(d, off, 64);
            }
            if (lm == 0) {
                red_s[wv][i * 16 + lk * 4 + r] = s;
                red_d[wv][i * 16 + lk * 4 + r] = d;
            }
        }
    }
    __syncthreads();
    if (t < 128) {
        int wm2 = t >> 6, row = t & 63;      // waves wm2 and wm2+2 share rows
        int grow = bm + wm2 * 64 + row;
        if (grow < N_NODES) {
            a_s[grow * 4 + head] = red_s[wm2][row] + red_s[wm2 + 2][row];
            a_d[grow * 4 + head] = red_d[wm2][row] + red_d[wm2 + 2][row];
        }
    }
}

// ---------------- K3: chunked block scan: counts -> exclusive offsets ----------------
__global__ __launch_bounds__(1024) void scan_kernel(const int* __restrict__ counts,
                                                    int* __restrict__ offsets) {
    const int CHUNK = 20;                 // 1024*20 = 20480 >= N_NODES
    int tid = threadIdx.x;
    int base = tid * CHUNK;
    int c[CHUNK];
    #pragma unroll
    for (int k = 0; k < CHUNK; k++) {
        int i = base + k;
        c[k] = (i < N_NODES) ? counts[i] : 0;
    }
    int pre[CHUNK];
    int sum = 0;
    #pragma unroll
    for (int k = 0; k < CHUNK; k++) { pre[k] = sum; sum += c[k]; }

    int lane = tid & 63, wv = tid >> 6;
    int s = sum;
    #pragma unroll
    for (int off = 1; off < 64; off <<= 1) {
        int u = __shfl_up(s, off, 64);
        if (lane >= off) s += u;
    }
    __shared__ int wsum[16];
    if (lane == 63) wsum[wv] = s;
    __syncthreads();
    if (tid < 16) {
        int u = wsum[tid];
        #pragma unroll
        for (int off = 1; off < 16; off <<= 1) {
            int w = __shfl_up(u, off, 64);
            if (tid >= off) u += w;
        }
        wsum[tid] = u;
    }
    __syncthreads();
    int wbase = (wv == 0) ? 0 : wsum[wv - 1];
    int excl = wbase + s - sum;
    #pragma unroll
    for (int k = 0; k < CHUNK; k++) {
        int i = base + k;
        if (i < N_NODES) offsets[i] = excl + pre[k];
    }
    if (tid == 1023) offsets[N_NODES] = wbase + s;
}

// ---------------- K4: pure scatter ----------------
__global__ __launch_bounds__(256) void scatter_kernel(const void* __restrict__ ei,
                                                      const int* __restrict__ offsets,
                                                      int* __restrict__ cursor,
                                                      int* __restrict__ sorted_src) {
    int is64 = detect_is64((const int*)ei);
    int e = blockIdx.x * 256 + threadIdx.x;
    if (e < N_EDGES) {
        int dst = edge_at(ei, is64, (long long)N_EDGES + e);
        int src = edge_at(ei, is64, e);
        int pos = offsets[dst] + atomicAdd(&cursor[dst], 1);
        if ((unsigned)pos < N_EDGES) sorted_src[pos] = src;   // guard vs replay artifacts
    }
}

// ---------------- K5: segment softmax + weighted gather ----------------
// 2 waves per node (alternating 4-edge chunks), partials combined via LDS.
// Weights computed inline: w = exp(leaky(a_s[src]+a_d[node])). No max subtraction
// (logits bounded ~|8|; fp32 exp safe; algebraically identical).
__global__ __launch_bounds__(256) void gather_kernel(const unsigned short* __restrict__ xlb,
                                                     const float* __restrict__ a_s,
                                                     const float* __restrict__ a_d,
                                                     const int* __restrict__ offsets,
                                                     const int* __restrict__ sorted_src,
                                                     const float* __restrict__ bias,
                                                     float* __restrict__ out) {
    __shared__ float cl[2][64][9];
    int wv = threadIdx.x >> 6;
    int nib = wv >> 1;
    int sub = wv & 1;
    int node = blockIdx.x * 2 + nib;    // grid = N_NODES/2
    int lane = threadIdx.x & 63;
    int hd = lane >> 4;
    int beg = offsets[node], end = offsets[node + 1];

    const unsigned short* xrow = xlb + lane * 8;
    float adh = a_d[node * 4 + hd];
    float acc[8] = {0, 0, 0, 0, 0, 0, 0, 0};
    float denom = 0.f;

    if (sub == 0) {   // self-loop
        float w = __expf(leaky(a_s[node * 4 + hd] + adh));
        denom = w;
        uint4 r = *(const uint4*)(xrow + (size_t)node * HC);
        float f[8];
        bf8_decode(r, f);
        #pragma unroll
        for (int k = 0; k < 8; k++) acc[k] = w * f[k];
    }

    for (int c0 = beg + sub * 4; c0 < end; c0 += 8) {
        int n = end - c0;
        if (n >= 4) {
            int s0 = sorted_src[c0];
            int s1 = sorted_src[c0 + 1];
            int s2 = sorted_src[c0 + 2];
            int s3 = sorted_src[c0 + 3];
            s0 = ((unsigned)s0 < N_NODES) ? s0 : 0;   // guard vs replay artifacts
            s1 = ((unsigned)s1 < N_NODES) ? s1 : 0;
            s2 = ((unsigned)s2 < N_NODES) ? s2 : 0;
            s3 = ((unsigned)s3 < N_NODES) ? s3 : 0;
            uint4 r0 = *(const uint4*)(xrow + (size_t)s0 * HC);
            uint4 r1 = *(const uint4*)(xrow + (size_t)s1 * HC);
            uint4 r2 = *(const uint4*)(xrow + (size_t)s2 * HC);
            uint4 r3 = *(const uint4*)(xrow + (size_t)s3 * HC);
            float w0 = __expf(leaky(a_s[s0 * 4 + hd] + adh));
            float w1 = __expf(leaky(a_s[s1 * 4 + hd] + adh));
            float w2 = __expf(leaky(a_s[s2 * 4 + hd] + adh));
            float w3 = __expf(leaky(a_s[s3 * 4 + hd] + adh));
            denom += (w0 + w1) + (w2 + w3);
            float f0[8], f1[8], f2[8], f3[8];
            bf8_decode(r0, f0);
            bf8_decode(r1, f1);
            bf8_decode(r2, f2);
            bf8_decode(r3, f3);
            #pragma unroll
            for (int k = 0; k < 8; k++)
                acc[k] += (w0 * f0[k] + w1 * f1[k]) + (w2 * f2[k] + w3 * f3[k]);
        } else {
            for (int j = 0; j < n; j++) {
                int s0 = sorted_src[c0 + j];
                s0 = ((unsigned)s0 < N_NODES) ? s0 : 0;
                uint4 r0 = *(const uint4*)(xrow + (size_t)s0 * HC);
                float w0 = __expf(leaky(a_s[s0 * 4 + hd] + adh));
                denom += w0;
                float f0[8];
                bf8_decode(r0, f0);
                #pragma unroll
                for (int k = 0; k < 8; k++) acc[k] += w0 * f0[k];
            }
        }
    }

    if (sub == 1) {
        #pragma unroll
        for (int k = 0; k < 8; k++) cl[nib][lane][k] = acc[k];
        cl[nib][lane][8] = denom;
    }
    __syncthreads();
    if (sub == 0) {
        #pragma unroll
        for (int k = 0; k < 8; k++) acc[k] += cl[nib][lane][k];
        denom += cl[nib][lane][8];

        float rd = 0.25f / (denom + 1e-16f);   // fold head-mean into normalize
        float v[8];
        #pragma unroll
        for (int k = 0; k < 8; k++) {
            float t = acc[k] * rd;
            t += __shfl_xor(t, 16, 64);
            t += __shfl_xor(t, 32, 64);
            v[k] = t;
        }
        if (hd == 0) {
            float4 b0 = *(const float4*)&bias[lane * 8];
            float4 b1 = *(const float4*)&bias[lane * 8 + 4];
            float o[8];
            o[0] = v[0] + b0.x; o[1] = v[1] + b0.y; o[2] = v[2] + b0.z; o[3] = v[3] + b0.w;
            o[4] = v[4] + b1.x; o[5] = v[5] + b1.y; o[6] = v[6] + b1.z; o[7] = v[7] + b1.w;
            #pragma unroll
            for (int k = 0; k < 8; k++) o[k] = o[k] > 0.f ? o[k] : expm1f(o[k]);
            *(float4*)&out[(size_t)node * OUT_CH + lane * 8]     = make_float4(o[0], o[1], o[2], o[3]);
            *(float4*)&out[(size_t)node * OUT_CH + lane * 8 + 4] = make_float4(o[4], o[5], o[6], o[7]);
        }
    }
}

// ---------------- launch ----------------
extern "C" void kernel_launch(void* const* d_in, const int* in_sizes, int n_in,
                              void* d_out, int out_size, void* d_ws, size_t ws_size,
                              hipStream_t stream) {
    const float* x       = (const float*)d_in[0];
    const float* W       = (const float*)d_in[1];
    const float* att_src = (const float*)d_in[2];
    const float* att_dst = (const float*)d_in[3];
    const float* bias    = (const float*)d_in[4];
    const void*  ei      = d_in[5];
    float* out = (float*)d_out;

    char* ws = (char*)d_ws;
    size_t off = 0;
    unsigned short* xlb = (unsigned short*)(ws + off); off += (size_t)N_PAD * HC * sizeof(unsigned short);
    float* a_s     = (float*)(ws + off); off += (size_t)N_NODES * HEADS * sizeof(float);
    float* a_d     = (float*)(ws + off); off += (size_t)N_NODES * HEADS * sizeof(float);
    int* counts    = (int*)(ws + off);   off += (size_t)N_NODES * sizeof(int);
    int* cursor    = (int*)(ws + off);   off += (size_t)N_NODES * sizeof(int);   // contiguous with counts
    int* offsets   = (int*)(ws + off);   off += (size_t)(N_NODES + 1) * sizeof(int);
    off = (off + 15) & ~(size_t)15;
    int* sorted_src = (int*)(ws + off);  off += (size_t)N_EDGES * sizeof(int);
    off = (off + 15) & ~(size_t)15;
    unsigned short* xb = (unsigned short*)(ws + off); off += (size_t)N_PAD * IN_CH * sizeof(unsigned short);
    unsigned short* Wt = (unsigned short*)(ws + off); off += (size_t)IN_CH * HC * sizeof(unsigned short);

    hipMemsetAsync(counts, 0, 2u * N_NODES * sizeof(int), stream);   // counts + cursor
    fusedA_kernel<<<FA_BLOCKS, 256, 0, stream>>>(x, W, xb, Wt, ei, counts);
    gemm_kernel<<<dim3(HC / 128, N_PAD / 128), 256, 0, stream>>>(xb, Wt, xlb, att_src, att_dst, a_s, a_d);
    scan_kernel<<<1, 1024, 0, stream>>>(counts, offsets);
    scatter_kernel<<<(N_EDGES + 255) / 256, 256, 0, stream>>>(ei, offsets, cursor, sorted_src);
    gather_kernel<<<N_NODES / 2, 256, 0, stream>>>(xlb, a_s, a_d, offsets, sorted_src, bias, out);
}